// Round 10
// baseline (91.323 us; speedup 1.0000x reference)
//
#include <hip/hip_runtime.h>

// ---------------------------------------------------------------------------
// cross_entropy_with_hnm_for_one_class_detection
//
// 3 scales: softmax-CE with hard-negative mining (k-th order statistic of
// neg_prob over N=B*H*W) + masked bbox MSE. Output: 3 floats.
//
// R9 residual was latency: (1) ~every wave of pass1 stalled on the divergent
// scattered bbox gather (8 cache lines per pos element); (2) 525-block grid
// = 2 blocks/CU left nothing to hide it with. R10: pass1 is pure coalesced
// (pos indices go to a per-scale queue; 1 reservation atomic/block); bbox
// MSE is computed in k_candsel from the queue with whole-grid TLP, issued
// before the redundant phase-B compute so latency overlaps; grid = 1050.
// 3 launches: k_zero -> k_pass1 -> k_candsel.
// ---------------------------------------------------------------------------

namespace {
constexpr int HW0 = 25600, HW1 = 6400, HW2 = 1600;
constexpr int N0 = 32 * HW0;  // 819200
constexpr int N1 = 32 * HW1;  // 204800
constexpr int N2 = 32 * HW2;  // 51200

constexpr int LBINS = 256;
constexpr int CAP = 8192;    // candidate capacity per scale
constexpr int PLCAP = 65536; // pos-list capacity per scale (u32 idx)
constexpr int PBUF = 192;    // per-block LDS pos buffer (expected ~20)

// 1024 elements per block (one float4-quad per thread)
constexpr int B0 = N0 / 1024, B1 = N1 / 1024, B2 = N2 / 1024;  // 800,200,50
constexpr int NBLK = B0 + B1 + B2;                             // 1050

struct P1 { double posce; unsigned int pcnt, ncnt; };  // 16 B

__device__ __forceinline__ void scale_of(int bid, int& s, int& rel, int& lo,
                                         int& hi) {
  if (bid < B0) {
    s = 0; rel = bid; lo = 0; hi = B0;
  } else if (bid < B0 + B1) {
    s = 1; rel = bid - B0; lo = B0; hi = B0 + B1;
  } else {
    s = 2; rel = bid - B0 - B1; lo = B0 + B1; hi = NBLK;
  }
}

__device__ __forceinline__ unsigned int lin_bin(float v) {
  unsigned int b = (unsigned int)(v * 256.0f);
  return b > 255u ? 255u : b;
}
}  // namespace

// ---------------- pass 0: zero control region -------------------------------
__global__ __launch_bounds__(256) void k_zero(uint4* __restrict__ p, int n4) {
  for (int i = threadIdx.x; i < n4; i += 256) p[i] = make_uint4(0u, 0u, 0u, 0u);
}

// ---------------- pass 1: coalesced-only softmax/CE/hist + pos queue --------
template <int HW>
__device__ void p1_main(int rel, int s, const float* __restrict__ sc,
                        const float* __restrict__ gl,
                        unsigned int* __restrict__ histS,
                        float* __restrict__ histceS, float* __restrict__ npvS,
                        unsigned int* __restrict__ posg,  // &pos_cnt_g[s]
                        unsigned int* __restrict__ plistS,
                        P1* __restrict__ p1out) {
  __shared__ unsigned int lh[4][LBINS];  // wave-private hists
  __shared__ float lhe[4][LBINS];
  __shared__ unsigned int pbuf[PBUF];
  __shared__ unsigned int pcnt_s, pbase;
  const int tid = threadIdx.x, wid = tid >> 6;
#pragma unroll
  for (int w = 0; w < 4; ++w) {
    lh[w][tid] = 0u;
    lhe[w][tid] = 0.0f;
  }
  if (tid == 0) pcnt_s = 0u;
  __syncthreads();

  const int q = (rel * 256 + tid) * 4;
  const int b = q / HW, hw = q - b * HW;
  const float* scp = sc + (size_t)b * 2 * HW + hw;
  const float4 s0v = *(const float4*)scp;
  const float4 s1v = *(const float4*)(scp + HW);
  const float* glp = gl + (size_t)b * 6 * HW + hw;
  const float4 l0v = *(const float4*)glp;
  const float4 l1v = *(const float4*)(glp + HW);
  const float s0a[4] = {s0v.x, s0v.y, s0v.z, s0v.w};
  const float s1a[4] = {s1v.x, s1v.y, s1v.z, s1v.w};
  const float l0a[4] = {l0v.x, l0v.y, l0v.z, l0v.w};
  const float l1a[4] = {l1v.x, l1v.y, l1v.z, l1v.w};

  double posce = 0.0;
  unsigned int pcnt = 0, ncnt = 0;
  float np[4];
#pragma unroll
  for (int j = 0; j < 4; ++j) {
    const float d = s1a[j] - s0a[j];
    const float t = expf(-fabsf(d));
    const float l1p = log1pf(t);  // lse after max-sub
    const bool pos = l0a[j] > 0.5f;
    const bool neg = l1a[j] > 0.5f;
    const float sm1 = ((d >= 0.0f) ? 1.0f : t) / (1.0f + t);
    const float v = neg ? sm1 : 0.0f;
    np[j] = v;
    const unsigned int bin = lin_bin(v);
    atomicAdd(&lh[wid][bin], 1u);
    if (neg) {
      ncnt++;
      atomicAdd(&lhe[wid][bin], l1p - ((d >= 0.0f) ? 0.0f : d));
    }
    if (pos) {
      pcnt++;
      posce += (double)(-l0a[j] * (((d > 0.0f) ? -d : 0.0f) - l1p));
      const unsigned int sl = atomicAdd(&pcnt_s, 1u);
      if (sl < (unsigned)PBUF) {
        pbuf[sl] = (unsigned int)(q + j);
      } else {  // overflow fallback (practically never)
        const unsigned int g = atomicAdd(posg, 1u);
        if (g < (unsigned)PLCAP) plistS[g] = (unsigned int)(q + j);
      }
    }
  }
  *(float4*)(npvS + q) = make_float4(np[0], np[1], np[2], np[3]);
  __syncthreads();
  {  // flush hists: one bin per thread per array
    const unsigned int c = lh[0][tid] + lh[1][tid] + lh[2][tid] + lh[3][tid];
    if (c) atomicAdd(&histS[tid], c);
    const float e = lhe[0][tid] + lhe[1][tid] + lhe[2][tid] + lhe[3][tid];
    if (e != 0.0f) atomicAdd(&histceS[tid], e);
  }
  if (tid == 0) {  // pos-list block reservation (1 atomic)
    const unsigned int n = min(pcnt_s, (unsigned int)PBUF);
    pbase = n ? atomicAdd(posg, n) : 0u;
  }
  __syncthreads();
  {
    const unsigned int n = min(pcnt_s, (unsigned int)PBUF);
    for (unsigned int i = tid; i < n; i += 256) {
      const unsigned int ix = pbase + i;
      if (ix < (unsigned)PLCAP) plistS[ix] = pbuf[i];
    }
  }

  // reduce posce/pcnt/ncnt -> part1
  for (int o = 32; o > 0; o >>= 1) {
    posce += __shfl_down(posce, o, 64);
    pcnt += __shfl_down(pcnt, o, 64);
    ncnt += __shfl_down(ncnt, o, 64);
  }
  __shared__ double wa[4];
  __shared__ unsigned int wc[4], wd[4];
  if ((tid & 63) == 0) { wa[wid] = posce; wc[wid] = pcnt; wd[wid] = ncnt; }
  __syncthreads();
  if (tid == 0) {
    p1out->posce = wa[0] + wa[1] + wa[2] + wa[3];
    p1out->pcnt = wc[0] + wc[1] + wc[2] + wc[3];
    p1out->ncnt = wd[0] + wd[1] + wd[2] + wd[3];
  }
}

__global__ __launch_bounds__(256, 4) void k_pass1(
    const float* sc0, const float* gl0, const float* sc1, const float* gl1,
    const float* sc2, const float* gl2, unsigned int* hist, float* histce,
    float* npv, P1* part1, unsigned int* pos_cnt_g, unsigned int* plist) {
  int s, rel, lo, hi;
  scale_of(blockIdx.x, s, rel, lo, hi);
  P1* p1 = part1 + blockIdx.x;
  if (s == 0)
    p1_main<HW0>(rel, 0, sc0, gl0, hist, histce, npv, pos_cnt_g, plist, p1);
  else if (s == 1)
    p1_main<HW1>(rel, 1, sc1, gl1, hist + LBINS, histce + LBINS, npv + N0,
                 pos_cnt_g + 1, plist + PLCAP, p1);
  else
    p1_main<HW2>(rel, 2, sc2, gl2, hist + 2 * LBINS, histce + 2 * LBINS,
                 npv + N0 + N1, pos_cnt_g + 2, plist + 2 * PLCAP, p1);
}

// --- pass 2: pos-gather diff2 + redundant mid + candidates; last finalizes --
__global__ __launch_bounds__(256, 4) void k_candsel(
    const float* bb0, const float* gl0, const float* bb1, const float* gl1,
    const float* bb2, const float* gl2, const P1* __restrict__ part1,
    const unsigned int* __restrict__ hist, const float* __restrict__ histce,
    const float* __restrict__ npv, const unsigned int* __restrict__ pos_cnt_g,
    const unsigned int* __restrict__ plist, double* __restrict__ p2,
    unsigned int* __restrict__ cand_cnt, unsigned int* __restrict__ cand,
    unsigned int* __restrict__ done, float* __restrict__ out) {
  const int tid = threadIdx.x;
  int s, rel, lo, hi;
  scale_of(blockIdx.x, s, rel, lo, hi);
  const int base = (s == 0) ? 0 : (s == 1) ? N0 : N0 + N1;
  const int HW = (s == 0) ? HW0 : (s == 1) ? HW1 : HW2;
  const float* bb = (s == 0) ? bb0 : (s == 1) ? bb1 : bb2;
  const float* gl = (s == 0) ? gl0 : (s == 1) ? gl1 : gl2;
  const int nblk_s = hi - lo;

  // ---- phase 1 (issued first; latency overlaps phase 2): pos-slice diff2
  double diff2 = 0.0;
  {
    const unsigned int pn = min(pos_cnt_g[s], (unsigned int)PLCAP);
    const unsigned int chunk = (pn + nblk_s - 1) / nblk_s;
    const unsigned int i0 = (unsigned int)rel * chunk;
    const unsigned int i1 = min(i0 + chunk, pn);
    const unsigned int* lst = plist + s * PLCAP;
    for (unsigned int i = i0 + tid; i < i1; i += 256) {
      const unsigned int idx = lst[i];
      const unsigned int b = idx / (unsigned)HW;
      const unsigned int hw = idx - b * (unsigned)HW;
      const float* glp = gl + (size_t)b * 6 * HW + hw;
      const float* bbp = bb + (size_t)b * 4 * HW + hw;
      float acc = 0.0f;
#pragma unroll
      for (int c = 0; c < 4; ++c) {
        const float dd = glp[(2 + c) * HW] - bbp[c * HW];
        acc += dd * dd;
      }
      diff2 += (double)acc;
    }
  }

  // ---- phase 2: redundant part1 reduce + dual 256-bin scan
  __shared__ double sda[256];
  __shared__ unsigned int sua[256], sub[256];
  {
    double a = 0.0;
    unsigned int c = 0, d = 0;
    for (int i = lo + tid; i < hi; i += 256) {
      const P1 p = part1[i];
      a += p.posce; c += p.pcnt; d += p.ncnt;
    }
    sda[tid] = a; sua[tid] = c; sub[tid] = d;
  }
  __syncthreads();
  for (int o = 128; o > 0; o >>= 1) {
    if (tid < o) {
      sda[tid] += sda[tid + o];
      sua[tid] += sua[tid + o];
      sub[tid] += sub[tid + o];
    }
    __syncthreads();
  }
  __shared__ double sh_posce;
  __shared__ unsigned int sh_pcnt, sh_k;
  if (tid == 0) {
    sh_posce = sda[0];
    sh_pcnt = sua[0];
    const unsigned long long k10 = 10ull * (unsigned long long)sua[0];
    sh_k = (k10 < (unsigned long long)sub[0]) ? (unsigned int)k10 : sub[0];
  }
  __syncthreads();

  __shared__ unsigned int partC[256];
  __shared__ double partE[256];
  __shared__ unsigned int sh_selb, sh_selr;
  __shared__ double sh_ceb;
  const unsigned int ownC = hist[s * LBINS + tid];
  const double ownE = (double)histce[s * LBINS + tid];
  partC[tid] = ownC;
  partE[tid] = ownE;
  __syncthreads();
  for (int o = 1; o < 256; o <<= 1) {
    const unsigned int aC = (tid >= o) ? partC[tid - o] : 0u;
    const double aE = (tid >= o) ? partE[tid - o] : 0.0;
    __syncthreads();
    partC[tid] += aC;
    partE[tid] += aE;
    __syncthreads();
  }
  {
    const unsigned int k = sh_k;
    const unsigned int inclC = partC[tid];
    const unsigned int exclC = inclC - ownC;
    if (ownC && k >= exclC && k < inclC) {  // unique winner thread
      sh_selb = (unsigned int)tid;
      sh_selr = k - exclC;
      sh_ceb = partE[tid] - ownE;
    }
  }
  __syncthreads();

  // ---- phase 3: gather candidates (block-aggregated reservation)
  __shared__ unsigned int cbuf[256];
  __shared__ unsigned int ccnt, cbase;
  if (tid == 0) ccnt = 0u;
  __syncthreads();
  {
    const unsigned int bsel = sh_selb;
    const int q = (rel * 256 + tid) * 4;
    const float4 v4 = *(const float4*)(npv + base + q);
    const float va[4] = {v4.x, v4.y, v4.z, v4.w};
#pragma unroll
    for (int j = 0; j < 4; ++j) {
      if (lin_bin(va[j]) == bsel) {
        const unsigned int sl = atomicAdd(&ccnt, 1u);
        if (sl < 256u) {
          cbuf[sl] = __float_as_uint(va[j]);
        } else {  // overflow fallback
          const unsigned int g = atomicAdd(&cand_cnt[s], 1u);
          if (g < (unsigned)CAP) cand[s * CAP + g] = __float_as_uint(va[j]);
        }
      }
    }
  }
  __syncthreads();
  if (tid == 0) {
    const unsigned int n = min(ccnt, 256u);
    cbase = n ? atomicAdd(&cand_cnt[s], n) : 0u;
  }
  __syncthreads();
  {
    const unsigned int n = min(ccnt, 256u);
    for (unsigned int i = tid; i < n; i += 256) {
      const unsigned int idx = cbase + i;
      if (idx < (unsigned)CAP) cand[s * CAP + idx] = cbuf[i];
    }
  }

  // ---- phase 4: block-reduce diff2 -> p2[bid]
  for (int o = 32; o > 0; o >>= 1) diff2 += __shfl_down(diff2, o, 64);
  __shared__ double wv[4];
  if ((tid & 63) == 0) wv[tid >> 6] = diff2;
  __syncthreads();
  if (tid == 0) p2[blockIdx.x] = wv[0] + wv[1] + wv[2] + wv[3];

  // ---- phase 5: last-block-done -> select + finalize
  __shared__ unsigned int rank_old;
  __syncthreads();
  if (tid == 0) {
    __threadfence();  // release: cand/p2 stores visible before count
    rank_old = atomicAdd(&done[s], 1u);
  }
  __syncthreads();
  if (rank_old != (unsigned int)(nblk_s - 1)) return;
  __threadfence();  // acquire

  // reduce p2 for this scale
  {
    double a = 0.0;
    for (int i = lo + tid; i < hi; i += 256) a += p2[i];
    sda[tid] = a;
  }
  __syncthreads();
  for (int o = 128; o > 0; o >>= 1) {
    if (tid < o) sda[tid] += sda[tid + o];
    __syncthreads();
  }
  __shared__ double sh_diff2;
  if (tid == 0) sh_diff2 = sda[0];
  __syncthreads();

  const unsigned int n = min(cand_cnt[s], (unsigned int)CAP);
  const unsigned int* lst = cand + s * CAP;
  __shared__ unsigned int dh[256];
  __shared__ unsigned int shp, shr, sh_w8, sh_nr;
  if (tid == 0) {
    shr = sh_selr;
    // bins >=1 span one binade -> candidates share bits 31:24
    shp = (sh_selb >= 1u) ? (lst[0] & 0xFF000000u) : 0u;
  }
  __syncthreads();
  const int r0 = (sh_selb >= 1u) ? 1 : 0;
  for (int round = r0; round < 4; ++round) {
    const int shift = 24 - 8 * round;
    dh[tid] = 0u;
    __syncthreads();
    const unsigned int pref = shp;
    for (unsigned int i = tid; i < n; i += 256) {
      const unsigned int v = lst[i];
      const bool match =
          (round == 0) || ((v >> (shift + 8)) == (pref >> (shift + 8)));
      if (match) atomicAdd(&dh[(v >> shift) & 255u], 1u);
    }
    __syncthreads();
    const unsigned int own = dh[tid];
    for (int o = 1; o < 256; o <<= 1) {  // inclusive scan in place
      const unsigned int add = (tid >= o) ? dh[tid - o] : 0u;
      __syncthreads();
      dh[tid] += add;
      __syncthreads();
    }
    const unsigned int incl = dh[tid];
    const unsigned int excl = incl - own;
    const unsigned int k = shr;
    if (own && k >= excl && k < incl) {
      sh_w8 = (unsigned int)tid;
      sh_nr = k - excl;
    }
    __syncthreads();
    if (tid == 0) {
      shp = pref | (sh_w8 << shift);
      shr = sh_nr;
    }
    __syncthreads();
  }
  const float thr = __uint_as_float(shp);

  // in-bin CE: candidates with 0 < v <= thr
  double acc = 0.0;
  for (unsigned int i = tid; i < n; i += 256) {
    const float v = __uint_as_float(lst[i]);
    if (v > 0.0f && v <= thr) acc += (double)(-logf(v));
  }
  sda[tid] = acc;
  __syncthreads();
  for (int o = 128; o > 0; o >>= 1) {
    if (tid < o) sda[tid] += sda[tid + o];
    __syncthreads();
  }
  if (tid == 0) {
    const double Ns = (s == 0) ? (double)N0 : (s == 1) ? (double)N1 : (double)N2;
    const double W = (s == 0) ? 160.0 : (s == 1) ? 80.0 : 40.0;
    const double ls = (sh_posce + sh_ceb + sda[0]) / (2.0 * Ns);
    const double lb = (sh_diff2 / W) / (4.0 * (double)sh_pcnt);
    out[s] = (float)(ls + lb);
  }
}

extern "C" void kernel_launch(void* const* d_in, const int* in_sizes, int n_in,
                              void* d_out, int out_size, void* d_ws,
                              size_t ws_size, hipStream_t stream) {
  const float* sc0 = (const float*)d_in[0];
  const float* bb0 = (const float*)d_in[1];
  const float* gl0 = (const float*)d_in[3];
  const float* sc1 = (const float*)d_in[4];
  const float* bb1 = (const float*)d_in[5];
  const float* gl1 = (const float*)d_in[7];
  const float* sc2 = (const float*)d_in[8];
  const float* bb2 = (const float*)d_in[9];
  const float* gl2 = (const float*)d_in[11];

  char* ws = (char*)d_ws;
  unsigned int* hist = (unsigned int*)ws;              // 3*256 u32 = 3 KiB
  float* histce = (float*)(hist + 3 * LBINS);          // 3 KiB
  unsigned int* cand_cnt = (unsigned int*)(histce + 3 * LBINS);  // 4 u32
  unsigned int* done = cand_cnt + 4;                   // 4 u32
  unsigned int* pos_cnt_g = done + 4;                  // 4 u32
  size_t zbytes = (size_t)3 * LBINS * 4 * 2 + 48;      // zeroed region
  zbytes = (zbytes + 255) & ~(size_t)255;
  size_t off = zbytes;
  P1* part1 = (P1*)(ws + off);                         // NBLK * 16 B
  off += (size_t)NBLK * sizeof(P1);
  double* p2 = (double*)(ws + off);                    // NBLK * 8 B
  off += (size_t)NBLK * 8;
  off = (off + 255) & ~(size_t)255;
  unsigned int* cand = (unsigned int*)(ws + off);      // 3*CAP u32
  off += (size_t)3 * CAP * 4;
  unsigned int* plist = (unsigned int*)(ws + off);     // 3*PLCAP u32
  off += (size_t)3 * PLCAP * 4;
  off = (off + 255) & ~(size_t)255;
  float* npv = (float*)(ws + off);                     // NT floats

  const dim3 blk(256);
  k_zero<<<dim3(1), blk, 0, stream>>>((uint4*)d_ws, (int)(zbytes >> 4));
  k_pass1<<<dim3(NBLK), blk, 0, stream>>>(sc0, gl0, sc1, gl1, sc2, gl2, hist,
                                          histce, npv, part1, pos_cnt_g, plist);
  k_candsel<<<dim3(NBLK), blk, 0, stream>>>(bb0, gl0, bb1, gl1, bb2, gl2,
                                            part1, hist, histce, npv,
                                            pos_cnt_g, plist, p2, cand_cnt,
                                            cand, done, (float*)d_out);
}

// Round 11
// 73.779 us; speedup vs baseline: 1.2378x; 1.2378x over previous
//
#include <hip/hip_runtime.h>

// ---------------------------------------------------------------------------
// cross_entropy_with_hnm_for_one_class_detection
//
// 3 scales: softmax-CE with hard-negative mining (k-th order statistic of
// neg_prob over N=B*H*W) + masked bbox MSE. Output: 3 floats.
//
// R10 bottleneck: 1050 per-block __threadfence() (device-scope L2 writeback,
// serialized per XCD) in the last-block-done fusion -- 56us at 2% VALU.
// R11: NO fences. Kernel boundaries provide visibility:
//   k_zero -> k_pass1 (coalesced softmax/CE/hist + pos queue)
//          -> k_cand  (pos-gather diff2 -> p2, count-scan -> sel_bin,
//                      block-aggregated candidate gather)
//          -> k_select (3 blocks: full mid recompute + radix select + final).
// ---------------------------------------------------------------------------

namespace {
constexpr int HW0 = 25600, HW1 = 6400, HW2 = 1600;
constexpr int N0 = 32 * HW0;  // 819200
constexpr int N1 = 32 * HW1;  // 204800
constexpr int N2 = 32 * HW2;  // 51200

constexpr int LBINS = 256;
constexpr int CAP = 8192;    // candidate capacity per scale
constexpr int PLCAP = 65536; // pos-list capacity per scale
constexpr int PBUF = 192;    // per-block LDS pos buffer (expected ~20)

// 1024 elements per block (one float4-quad per thread)
constexpr int B0 = N0 / 1024, B1 = N1 / 1024, B2 = N2 / 1024;  // 800,200,50
constexpr int NBLK = B0 + B1 + B2;                             // 1050

struct P1 { double posce; unsigned int pcnt, ncnt; };  // 16 B

__device__ __forceinline__ void scale_of(int bid, int& s, int& rel, int& lo,
                                         int& hi) {
  if (bid < B0) {
    s = 0; rel = bid; lo = 0; hi = B0;
  } else if (bid < B0 + B1) {
    s = 1; rel = bid - B0; lo = B0; hi = B0 + B1;
  } else {
    s = 2; rel = bid - B0 - B1; lo = B0 + B1; hi = NBLK;
  }
}

__device__ __forceinline__ unsigned int lin_bin(float v) {
  unsigned int b = (unsigned int)(v * 256.0f);
  return b > 255u ? 255u : b;
}
}  // namespace

// ---------------- pass 0: zero control region -------------------------------
__global__ __launch_bounds__(256) void k_zero(uint4* __restrict__ p, int n4) {
  for (int i = threadIdx.x; i < n4; i += 256) p[i] = make_uint4(0u, 0u, 0u, 0u);
}

// ---------------- pass 1: coalesced-only softmax/CE/hist + pos queue --------
template <int HW>
__device__ void p1_main(int rel, const float* __restrict__ sc,
                        const float* __restrict__ gl,
                        unsigned int* __restrict__ histS,
                        float* __restrict__ histceS, float* __restrict__ npvS,
                        unsigned int* __restrict__ posg,
                        unsigned int* __restrict__ plistS,
                        P1* __restrict__ p1out) {
  __shared__ unsigned int lh[4][LBINS];  // wave-private hists
  __shared__ float lhe[4][LBINS];
  __shared__ unsigned int pbuf[PBUF];
  __shared__ unsigned int pcnt_s, pbase;
  const int tid = threadIdx.x, wid = tid >> 6;
#pragma unroll
  for (int w = 0; w < 4; ++w) {
    lh[w][tid] = 0u;
    lhe[w][tid] = 0.0f;
  }
  if (tid == 0) pcnt_s = 0u;
  __syncthreads();

  const int q = (rel * 256 + tid) * 4;
  const int b = q / HW, hw = q - b * HW;
  const float* scp = sc + (size_t)b * 2 * HW + hw;
  const float4 s0v = *(const float4*)scp;
  const float4 s1v = *(const float4*)(scp + HW);
  const float* glp = gl + (size_t)b * 6 * HW + hw;
  const float4 l0v = *(const float4*)glp;
  const float4 l1v = *(const float4*)(glp + HW);
  const float s0a[4] = {s0v.x, s0v.y, s0v.z, s0v.w};
  const float s1a[4] = {s1v.x, s1v.y, s1v.z, s1v.w};
  const float l0a[4] = {l0v.x, l0v.y, l0v.z, l0v.w};
  const float l1a[4] = {l1v.x, l1v.y, l1v.z, l1v.w};

  double posce = 0.0;
  unsigned int pcnt = 0, ncnt = 0;
  float np[4];
#pragma unroll
  for (int j = 0; j < 4; ++j) {
    const float d = s1a[j] - s0a[j];
    const float t = expf(-fabsf(d));
    const float l1p = log1pf(t);  // lse after max-sub
    const bool pos = l0a[j] > 0.5f;
    const bool neg = l1a[j] > 0.5f;
    const float sm1 = ((d >= 0.0f) ? 1.0f : t) / (1.0f + t);
    const float v = neg ? sm1 : 0.0f;
    np[j] = v;
    const unsigned int bin = lin_bin(v);
    atomicAdd(&lh[wid][bin], 1u);
    if (neg) {
      ncnt++;
      atomicAdd(&lhe[wid][bin], l1p - ((d >= 0.0f) ? 0.0f : d));
    }
    if (pos) {
      pcnt++;
      posce += (double)(-l0a[j] * (((d > 0.0f) ? -d : 0.0f) - l1p));
      const unsigned int sl = atomicAdd(&pcnt_s, 1u);
      if (sl < (unsigned)PBUF) {
        pbuf[sl] = (unsigned int)(q + j);
      } else {  // overflow fallback (practically never)
        const unsigned int g = atomicAdd(posg, 1u);
        if (g < (unsigned)PLCAP) plistS[g] = (unsigned int)(q + j);
      }
    }
  }
  *(float4*)(npvS + q) = make_float4(np[0], np[1], np[2], np[3]);
  __syncthreads();
  {  // flush hists: one bin per thread per array
    const unsigned int c = lh[0][tid] + lh[1][tid] + lh[2][tid] + lh[3][tid];
    if (c) atomicAdd(&histS[tid], c);
    const float e = lhe[0][tid] + lhe[1][tid] + lhe[2][tid] + lhe[3][tid];
    if (e != 0.0f) atomicAdd(&histceS[tid], e);
  }
  if (tid == 0) {  // pos-list block reservation (1 atomic)
    const unsigned int n = min(pcnt_s, (unsigned int)PBUF);
    pbase = n ? atomicAdd(posg, n) : 0u;
  }
  __syncthreads();
  {
    const unsigned int n = min(pcnt_s, (unsigned int)PBUF);
    for (unsigned int i = tid; i < n; i += 256) {
      const unsigned int ix = pbase + i;
      if (ix < (unsigned)PLCAP) plistS[ix] = pbuf[i];
    }
  }

  // reduce posce/pcnt/ncnt -> part1
  for (int o = 32; o > 0; o >>= 1) {
    posce += __shfl_down(posce, o, 64);
    pcnt += __shfl_down(pcnt, o, 64);
    ncnt += __shfl_down(ncnt, o, 64);
  }
  __shared__ double wa[4];
  __shared__ unsigned int wc[4], wd[4];
  if ((tid & 63) == 0) { wa[wid] = posce; wc[wid] = pcnt; wd[wid] = ncnt; }
  __syncthreads();
  if (tid == 0) {
    p1out->posce = wa[0] + wa[1] + wa[2] + wa[3];
    p1out->pcnt = wc[0] + wc[1] + wc[2] + wc[3];
    p1out->ncnt = wd[0] + wd[1] + wd[2] + wd[3];
  }
}

__global__ __launch_bounds__(256, 4) void k_pass1(
    const float* sc0, const float* gl0, const float* sc1, const float* gl1,
    const float* sc2, const float* gl2, unsigned int* hist, float* histce,
    float* npv, P1* part1, unsigned int* pos_cnt_g, unsigned int* plist) {
  int s, rel, lo, hi;
  scale_of(blockIdx.x, s, rel, lo, hi);
  P1* p1 = part1 + blockIdx.x;
  if (s == 0)
    p1_main<HW0>(rel, sc0, gl0, hist, histce, npv, pos_cnt_g, plist, p1);
  else if (s == 1)
    p1_main<HW1>(rel, sc1, gl1, hist + LBINS, histce + LBINS, npv + N0,
                 pos_cnt_g + 1, plist + PLCAP, p1);
  else
    p1_main<HW2>(rel, sc2, gl2, hist + 2 * LBINS, histce + 2 * LBINS,
                 npv + N0 + N1, pos_cnt_g + 2, plist + 2 * PLCAP, p1);
}

// --- pass 2: pos-gather diff2 -> p2; count-scan -> sel_bin; gather cands ----
__global__ __launch_bounds__(256, 4) void k_cand(
    const float* bb0, const float* gl0, const float* bb1, const float* gl1,
    const float* bb2, const float* gl2, const P1* __restrict__ part1,
    const unsigned int* __restrict__ hist, const float* __restrict__ npv,
    const unsigned int* __restrict__ pos_cnt_g,
    const unsigned int* __restrict__ plist, double* __restrict__ p2,
    unsigned int* __restrict__ cand_cnt, unsigned int* __restrict__ cand) {
  const int tid = threadIdx.x;
  int s, rel, lo, hi;
  scale_of(blockIdx.x, s, rel, lo, hi);
  const int base = (s == 0) ? 0 : (s == 1) ? N0 : N0 + N1;
  const int HW = (s == 0) ? HW0 : (s == 1) ? HW1 : HW2;
  const float* bb = (s == 0) ? bb0 : (s == 1) ? bb1 : bb2;
  const float* gl = (s == 0) ? gl0 : (s == 1) ? gl1 : gl2;
  const int nblk_s = hi - lo;

  // ---- phase 1 (issued first; latency overlaps phase 2): pos-slice diff2
  double diff2 = 0.0;
  {
    const unsigned int pn = min(pos_cnt_g[s], (unsigned int)PLCAP);
    const unsigned int chunk = (pn + nblk_s - 1) / nblk_s;
    const unsigned int i0 = (unsigned int)rel * chunk;
    const unsigned int i1 = min(i0 + chunk, pn);
    const unsigned int* lst = plist + s * PLCAP;
    for (unsigned int i = i0 + tid; i < i1; i += 256) {
      const unsigned int idx = lst[i];
      const unsigned int b = idx / (unsigned)HW;
      const unsigned int hw = idx - b * (unsigned)HW;
      const float* glp = gl + (size_t)b * 6 * HW + hw;
      const float* bbp = bb + (size_t)b * 4 * HW + hw;
      float acc = 0.0f;
#pragma unroll
      for (int c = 0; c < 4; ++c) {
        const float dd = glp[(2 + c) * HW] - bbp[c * HW];
        acc += dd * dd;
      }
      diff2 += (double)acc;
    }
  }

  // ---- phase 2: redundant count reduce + count-only 256-bin scan -> sel_bin
  __shared__ unsigned int sua[256], sub[256];
  {
    unsigned int c = 0, d = 0;
    for (int i = lo + tid; i < hi; i += 256) {
      const P1 p = part1[i];
      c += p.pcnt; d += p.ncnt;
    }
    sua[tid] = c; sub[tid] = d;
  }
  __syncthreads();
  for (int o = 128; o > 0; o >>= 1) {
    if (tid < o) {
      sua[tid] += sua[tid + o];
      sub[tid] += sub[tid + o];
    }
    __syncthreads();
  }
  __shared__ unsigned int sh_k;
  if (tid == 0) {
    const unsigned long long k10 = 10ull * (unsigned long long)sua[0];
    sh_k = (k10 < (unsigned long long)sub[0]) ? (unsigned int)k10 : sub[0];
  }
  __syncthreads();

  __shared__ unsigned int partC[256];
  __shared__ unsigned int sh_selb;
  const unsigned int ownC = hist[s * LBINS + tid];
  partC[tid] = ownC;
  __syncthreads();
  for (int o = 1; o < 256; o <<= 1) {
    const unsigned int aC = (tid >= o) ? partC[tid - o] : 0u;
    __syncthreads();
    partC[tid] += aC;
    __syncthreads();
  }
  {
    const unsigned int k = sh_k;
    const unsigned int inclC = partC[tid];
    const unsigned int exclC = inclC - ownC;
    if (ownC && k >= exclC && k < inclC) sh_selb = (unsigned int)tid;
  }
  __syncthreads();

  // ---- phase 3: gather candidates (block-aggregated reservation)
  __shared__ unsigned int cbuf[256];
  __shared__ unsigned int ccnt, cbase;
  if (tid == 0) ccnt = 0u;
  __syncthreads();
  {
    const unsigned int bsel = sh_selb;
    const int q = (rel * 256 + tid) * 4;
    const float4 v4 = *(const float4*)(npv + base + q);
    const float va[4] = {v4.x, v4.y, v4.z, v4.w};
#pragma unroll
    for (int j = 0; j < 4; ++j) {
      if (lin_bin(va[j]) == bsel) {
        const unsigned int sl = atomicAdd(&ccnt, 1u);
        if (sl < 256u) {
          cbuf[sl] = __float_as_uint(va[j]);
        } else {  // overflow fallback
          const unsigned int g = atomicAdd(&cand_cnt[s], 1u);
          if (g < (unsigned)CAP) cand[s * CAP + g] = __float_as_uint(va[j]);
        }
      }
    }
  }
  __syncthreads();
  if (tid == 0) {
    const unsigned int n = min(ccnt, 256u);
    cbase = n ? atomicAdd(&cand_cnt[s], n) : 0u;
  }
  __syncthreads();
  {
    const unsigned int n = min(ccnt, 256u);
    for (unsigned int i = tid; i < n; i += 256) {
      const unsigned int idx = cbase + i;
      if (idx < (unsigned)CAP) cand[s * CAP + idx] = cbuf[i];
    }
  }

  // ---- phase 4: block-reduce diff2 -> p2[bid]
  for (int o = 32; o > 0; o >>= 1) diff2 += __shfl_down(diff2, o, 64);
  __shared__ double wv[4];
  if ((tid & 63) == 0) wv[tid >> 6] = diff2;
  __syncthreads();
  if (tid == 0) p2[blockIdx.x] = wv[0] + wv[1] + wv[2] + wv[3];
}

// ------- pass 3: 3 blocks -- full mid recompute + radix select + finalize ---
__global__ __launch_bounds__(256) void k_select(
    const P1* __restrict__ part1, const unsigned int* __restrict__ hist,
    const float* __restrict__ histce, const double* __restrict__ p2,
    const unsigned int* __restrict__ cand_cnt,
    const unsigned int* __restrict__ cand, float* __restrict__ out) {
  const int s = blockIdx.x;
  const int tid = threadIdx.x;
  const int lo = (s == 0) ? 0 : (s == 1) ? B0 : B0 + B1;
  const int hi = (s == 0) ? B0 : (s == 1) ? B0 + B1 : NBLK;

  // reduce part1 + p2
  __shared__ double sda[256], sdb[256];
  __shared__ unsigned int sua[256], sub[256];
  {
    double a = 0.0, b2 = 0.0;
    unsigned int c = 0, d = 0;
    for (int i = lo + tid; i < hi; i += 256) {
      const P1 p = part1[i];
      a += p.posce; c += p.pcnt; d += p.ncnt;
      b2 += p2[i];
    }
    sda[tid] = a; sdb[tid] = b2; sua[tid] = c; sub[tid] = d;
  }
  __syncthreads();
  for (int o = 128; o > 0; o >>= 1) {
    if (tid < o) {
      sda[tid] += sda[tid + o]; sdb[tid] += sdb[tid + o];
      sua[tid] += sua[tid + o]; sub[tid] += sub[tid + o];
    }
    __syncthreads();
  }
  __shared__ double sh_posce, sh_diff2;
  __shared__ unsigned int sh_pcnt, sh_k;
  if (tid == 0) {
    sh_posce = sda[0];
    sh_diff2 = sdb[0];
    sh_pcnt = sua[0];
    const unsigned long long k10 = 10ull * (unsigned long long)sua[0];
    sh_k = (k10 < (unsigned long long)sub[0]) ? (unsigned int)k10 : sub[0];
  }
  __syncthreads();

  // dual 256-bin scan -> selb, selr, ce_below
  __shared__ unsigned int partC[256];
  __shared__ double partE[256];
  __shared__ unsigned int sh_selb, sh_selr;
  __shared__ double sh_ceb;
  const unsigned int ownC = hist[s * LBINS + tid];
  const double ownE = (double)histce[s * LBINS + tid];
  partC[tid] = ownC;
  partE[tid] = ownE;
  __syncthreads();
  for (int o = 1; o < 256; o <<= 1) {
    const unsigned int aC = (tid >= o) ? partC[tid - o] : 0u;
    const double aE = (tid >= o) ? partE[tid - o] : 0.0;
    __syncthreads();
    partC[tid] += aC;
    partE[tid] += aE;
    __syncthreads();
  }
  {
    const unsigned int k = sh_k;
    const unsigned int inclC = partC[tid];
    const unsigned int exclC = inclC - ownC;
    if (ownC && k >= exclC && k < inclC) {
      sh_selb = (unsigned int)tid;
      sh_selr = k - exclC;
      sh_ceb = partE[tid] - ownE;
    }
  }
  __syncthreads();

  // radix select over candidates
  const unsigned int n = min(cand_cnt[s], (unsigned int)CAP);
  const unsigned int* lst = cand + s * CAP;
  __shared__ unsigned int dh[256];
  __shared__ unsigned int shp, shr, sh_w8, sh_nr;
  if (tid == 0) {
    shr = sh_selr;
    // bins >=1 span one binade -> candidates share bits 31:24
    shp = (sh_selb >= 1u) ? (lst[0] & 0xFF000000u) : 0u;
  }
  __syncthreads();
  const int r0 = (sh_selb >= 1u) ? 1 : 0;
  for (int round = r0; round < 4; ++round) {
    const int shift = 24 - 8 * round;
    dh[tid] = 0u;
    __syncthreads();
    const unsigned int pref = shp;
    for (unsigned int i = tid; i < n; i += 256) {
      const unsigned int v = lst[i];
      const bool match =
          (round == 0) || ((v >> (shift + 8)) == (pref >> (shift + 8)));
      if (match) atomicAdd(&dh[(v >> shift) & 255u], 1u);
    }
    __syncthreads();
    const unsigned int own = dh[tid];
    for (int o = 1; o < 256; o <<= 1) {  // inclusive scan in place
      const unsigned int add = (tid >= o) ? dh[tid - o] : 0u;
      __syncthreads();
      dh[tid] += add;
      __syncthreads();
    }
    const unsigned int incl = dh[tid];
    const unsigned int excl = incl - own;
    const unsigned int k = shr;
    if (own && k >= excl && k < incl) {
      sh_w8 = (unsigned int)tid;
      sh_nr = k - excl;
    }
    __syncthreads();
    if (tid == 0) {
      shp = pref | (sh_w8 << shift);
      shr = sh_nr;
    }
    __syncthreads();
  }
  const float thr = __uint_as_float(shp);

  // in-bin CE: candidates with 0 < v <= thr
  double acc = 0.0;
  for (unsigned int i = tid; i < n; i += 256) {
    const float v = __uint_as_float(lst[i]);
    if (v > 0.0f && v <= thr) acc += (double)(-logf(v));
  }
  sda[tid] = acc;
  __syncthreads();
  for (int o = 128; o > 0; o >>= 1) {
    if (tid < o) sda[tid] += sda[tid + o];
    __syncthreads();
  }
  if (tid == 0) {
    const double Ns = (s == 0) ? (double)N0 : (s == 1) ? (double)N1 : (double)N2;
    const double W = (s == 0) ? 160.0 : (s == 1) ? 80.0 : 40.0;
    const double ls = (sh_posce + sh_ceb + sda[0]) / (2.0 * Ns);
    const double lb = (sh_diff2 / W) / (4.0 * (double)sh_pcnt);
    out[s] = (float)(ls + lb);
  }
}

extern "C" void kernel_launch(void* const* d_in, const int* in_sizes, int n_in,
                              void* d_out, int out_size, void* d_ws,
                              size_t ws_size, hipStream_t stream) {
  const float* sc0 = (const float*)d_in[0];
  const float* bb0 = (const float*)d_in[1];
  const float* gl0 = (const float*)d_in[3];
  const float* sc1 = (const float*)d_in[4];
  const float* bb1 = (const float*)d_in[5];
  const float* gl1 = (const float*)d_in[7];
  const float* sc2 = (const float*)d_in[8];
  const float* bb2 = (const float*)d_in[9];
  const float* gl2 = (const float*)d_in[11];

  char* ws = (char*)d_ws;
  unsigned int* hist = (unsigned int*)ws;              // 3*256 u32
  float* histce = (float*)(hist + 3 * LBINS);          // 3*256 f32
  unsigned int* cand_cnt = (unsigned int*)(histce + 3 * LBINS);  // 4 u32
  unsigned int* pos_cnt_g = cand_cnt + 4;              // 4 u32
  size_t zbytes = (size_t)3 * LBINS * 4 * 2 + 32;      // zeroed region
  zbytes = (zbytes + 255) & ~(size_t)255;
  size_t off = zbytes;
  P1* part1 = (P1*)(ws + off);                         // NBLK * 16 B
  off += (size_t)NBLK * sizeof(P1);
  double* p2 = (double*)(ws + off);                    // NBLK * 8 B
  off += (size_t)NBLK * 8;
  off = (off + 255) & ~(size_t)255;
  unsigned int* cand = (unsigned int*)(ws + off);      // 3*CAP u32
  off += (size_t)3 * CAP * 4;
  unsigned int* plist = (unsigned int*)(ws + off);     // 3*PLCAP u32
  off += (size_t)3 * PLCAP * 4;
  off = (off + 255) & ~(size_t)255;
  float* npv = (float*)(ws + off);                     // NT floats

  const dim3 blk(256);
  k_zero<<<dim3(1), blk, 0, stream>>>((uint4*)d_ws, (int)(zbytes >> 4));
  k_pass1<<<dim3(NBLK), blk, 0, stream>>>(sc0, gl0, sc1, gl1, sc2, gl2, hist,
                                          histce, npv, part1, pos_cnt_g, plist);
  k_cand<<<dim3(NBLK), blk, 0, stream>>>(bb0, gl0, bb1, gl1, bb2, gl2, part1,
                                         hist, npv, pos_cnt_g, plist, p2,
                                         cand_cnt, cand);
  k_select<<<dim3(3), blk, 0, stream>>>(part1, hist, histce, p2, cand_cnt,
                                        cand, (float*)d_out);
}

// Round 12
// 57.127 us; speedup vs baseline: 1.5986x; 1.2915x over previous
//
#include <hip/hip_runtime.h>

// ---------------------------------------------------------------------------
// cross_entropy_with_hnm_for_one_class_detection
//
// 3 scales: softmax-CE with hard-negative mining (k-th order statistic of
// neg_prob over N=B*H*W) + masked bbox MSE. Output: 3 floats.
//
// R11 lesson: R9's shape (525 blocks x 2048 elem, bbox gather inline in
// pass1) was the best measured; its only poison was the per-block
// __threadfence/done pattern. R12 = R9 structure with the fence replaced by
// a kernel boundary:
//   k_zero -> k_pass1 (8 elem/thread, loads upfront, inline pos math,
//   wave-private hists) -> k_cand (redundant count-scan -> sel_bin;
//   block-aggregated candidate gather) -> k_select (3 blocks: reduce +
//   dual scan + radix select + finalize). No fences anywhere.
// ---------------------------------------------------------------------------

namespace {
constexpr int HW0 = 25600, HW1 = 6400, HW2 = 1600;
constexpr int N0 = 32 * HW0;  // 819200
constexpr int N1 = 32 * HW1;  // 204800
constexpr int N2 = 32 * HW2;  // 51200

constexpr int LBINS = 256;
constexpr int CAP = 8192;  // candidate capacity per scale

// 2048 elements per block (two float4-quads per thread)
constexpr int B0 = N0 / 2048, B1 = N1 / 2048, B2 = N2 / 2048;  // 400,100,25
constexpr int NBLK = B0 + B1 + B2;                             // 525

__device__ __forceinline__ void scale_of(int bid, int& s, int& rel, int& lo,
                                         int& hi) {
  if (bid < B0) {
    s = 0; rel = bid; lo = 0; hi = B0;
  } else if (bid < B0 + B1) {
    s = 1; rel = bid - B0; lo = B0; hi = B0 + B1;
  } else {
    s = 2; rel = bid - B0 - B1; lo = B0 + B1; hi = NBLK;
  }
}

__device__ __forceinline__ unsigned int lin_bin(float v) {
  unsigned int b = (unsigned int)(v * 256.0f);
  return b > 255u ? 255u : b;
}
}  // namespace

// ---------------- pass 0: zero control region (~6.4 KB) ---------------------
__global__ __launch_bounds__(256) void k_zero(uint4* __restrict__ p, int n4) {
  for (int i = threadIdx.x; i < n4; i += 256) p[i] = make_uint4(0u, 0u, 0u, 0u);
}

// ---------------- pass 1: softmax/CE/bbox/hist, all fused -------------------
template <int HW>
__device__ void p1_main(int rel, const float* __restrict__ sc,
                        const float* __restrict__ bb,
                        const float* __restrict__ gl,
                        unsigned int* __restrict__ histS,
                        float* __restrict__ histceS, float* __restrict__ npvS,
                        double* __restrict__ posce_o, double* __restrict__ diff2_o,
                        unsigned int* __restrict__ pcnt_o,
                        unsigned int* __restrict__ ncnt_o) {
  __shared__ unsigned int lh[4][LBINS];  // wave-private hists, 4 KiB
  __shared__ float lhe[4][LBINS];        // 4 KiB
  const int tid = threadIdx.x, wid = tid >> 6;
#pragma unroll
  for (int w = 0; w < 4; ++w) {
    lh[w][tid] = 0u;
    lhe[w][tid] = 0.0f;
  }
  __syncthreads();

  // two quad-groups; all 8 coalesced loads issued before any math
  const int q0 = (rel * 512 + tid) * 4;
  const int q1 = q0 + 1024;
  const int bA = q0 / HW, hwA = q0 - bA * HW;
  const int bB = q1 / HW, hwB = q1 - bB * HW;
  const float* scA = sc + (size_t)bA * 2 * HW + hwA;
  const float* scB = sc + (size_t)bB * 2 * HW + hwB;
  const float* glA = gl + (size_t)bA * 6 * HW + hwA;
  const float* glB = gl + (size_t)bB * 6 * HW + hwB;
  const float4 s0A = *(const float4*)scA;
  const float4 s1A = *(const float4*)(scA + HW);
  const float4 l0A = *(const float4*)glA;
  const float4 l1A = *(const float4*)(glA + HW);
  const float4 s0B = *(const float4*)scB;
  const float4 s1B = *(const float4*)(scB + HW);
  const float4 l0B = *(const float4*)glB;
  const float4 l1B = *(const float4*)(glB + HW);

  double posce = 0.0, diff2 = 0.0;
  unsigned int pcnt = 0, ncnt = 0;

  auto process = [&](const float4& s0v, const float4& s1v, const float4& l0v,
                     const float4& l1v, const float* __restrict__ glq,
                     const float* __restrict__ bbq, float* __restrict__ npq) {
    const float s0a[4] = {s0v.x, s0v.y, s0v.z, s0v.w};
    const float s1a[4] = {s1v.x, s1v.y, s1v.z, s1v.w};
    const float l0a[4] = {l0v.x, l0v.y, l0v.z, l0v.w};
    const float l1a[4] = {l1v.x, l1v.y, l1v.z, l1v.w};
    float np[4];
#pragma unroll
    for (int j = 0; j < 4; ++j) {
      const float d = s1a[j] - s0a[j];
      const float t = expf(-fabsf(d));
      const float l1p = log1pf(t);  // lse after max-sub
      const bool pos = l0a[j] > 0.5f;
      const bool neg = l1a[j] > 0.5f;
      const float sm1 = ((d >= 0.0f) ? 1.0f : t) / (1.0f + t);
      const float v = neg ? sm1 : 0.0f;
      np[j] = v;
      const unsigned int bin = lin_bin(v);
      atomicAdd(&lh[wid][bin], 1u);
      if (neg) {
        ncnt++;
        atomicAdd(&lhe[wid][bin], l1p - ((d >= 0.0f) ? 0.0f : d));
      }
      if (pos) {
        pcnt++;
        posce += (double)(-l0a[j] * (((d > 0.0f) ? -d : 0.0f) - l1p));
        float acc = 0.0f;
#pragma unroll
        for (int c = 0; c < 4; ++c) {
          const float dd = glq[(2 + c) * HW + j] - bbq[c * HW + j];
          acc += dd * dd;
        }
        diff2 += (double)acc;
      }
    }
    *(float4*)npq = make_float4(np[0], np[1], np[2], np[3]);
  };
  process(s0A, s1A, l0A, l1A, glA, bb + (size_t)bA * 4 * HW + hwA, npvS + q0);
  process(s0B, s1B, l0B, l1B, glB, bb + (size_t)bB * 4 * HW + hwB, npvS + q1);

  __syncthreads();
  {  // flush hists: one bin per thread per array
    const unsigned int c = lh[0][tid] + lh[1][tid] + lh[2][tid] + lh[3][tid];
    if (c) atomicAdd(&histS[tid], c);
    const float e = lhe[0][tid] + lhe[1][tid] + lhe[2][tid] + lhe[3][tid];
    if (e != 0.0f) atomicAdd(&histceS[tid], e);
  }

  // reduce partials -> per-block SoA slots (no global atomics)
  for (int o = 32; o > 0; o >>= 1) {
    posce += __shfl_down(posce, o, 64);
    diff2 += __shfl_down(diff2, o, 64);
    pcnt += __shfl_down(pcnt, o, 64);
    ncnt += __shfl_down(ncnt, o, 64);
  }
  __shared__ double wa[4], wb[4];
  __shared__ unsigned int wc[4], wd[4];
  if ((tid & 63) == 0) {
    wa[wid] = posce; wb[wid] = diff2; wc[wid] = pcnt; wd[wid] = ncnt;
  }
  __syncthreads();
  if (tid == 0) {
    *posce_o = wa[0] + wa[1] + wa[2] + wa[3];
    *diff2_o = wb[0] + wb[1] + wb[2] + wb[3];
    *pcnt_o = wc[0] + wc[1] + wc[2] + wc[3];
    *ncnt_o = wd[0] + wd[1] + wd[2] + wd[3];
  }
}

__global__ __launch_bounds__(256) void k_pass1(
    const float* sc0, const float* bb0, const float* gl0,
    const float* sc1, const float* bb1, const float* gl1,
    const float* sc2, const float* bb2, const float* gl2,
    unsigned int* hist, float* histce, float* npv, double* posce_a,
    double* diff2_a, unsigned int* pcnt_a, unsigned int* ncnt_a) {
  int s, rel, lo, hi;
  scale_of(blockIdx.x, s, rel, lo, hi);
  const int bid = blockIdx.x;
  if (s == 0)
    p1_main<HW0>(rel, sc0, bb0, gl0, hist, histce, npv, posce_a + bid,
                 diff2_a + bid, pcnt_a + bid, ncnt_a + bid);
  else if (s == 1)
    p1_main<HW1>(rel, sc1, bb1, gl1, hist + LBINS, histce + LBINS, npv + N0,
                 posce_a + bid, diff2_a + bid, pcnt_a + bid, ncnt_a + bid);
  else
    p1_main<HW2>(rel, sc2, bb2, gl2, hist + 2 * LBINS, histce + 2 * LBINS,
                 npv + N0 + N1, posce_a + bid, diff2_a + bid, pcnt_a + bid,
                 ncnt_a + bid);
}

// --- pass 2: redundant count-scan -> sel_bin; gather candidates -------------
__global__ __launch_bounds__(256) void k_cand(
    const unsigned int* __restrict__ pcnt_a,
    const unsigned int* __restrict__ ncnt_a,
    const unsigned int* __restrict__ hist, const float* __restrict__ npv,
    unsigned int* __restrict__ cand_cnt, unsigned int* __restrict__ cand) {
  const int tid = threadIdx.x;
  int s, rel, lo, hi;
  scale_of(blockIdx.x, s, rel, lo, hi);
  const int base = (s == 0) ? 0 : (s == 1) ? N0 : N0 + N1;

  // redundant count reduce (L2-hot, ~4 KB)
  __shared__ unsigned int sua[256], sub[256];
  {
    unsigned int c = 0, d = 0;
    for (int i = lo + tid; i < hi; i += 256) {
      c += pcnt_a[i];
      d += ncnt_a[i];
    }
    sua[tid] = c; sub[tid] = d;
  }
  __syncthreads();
  for (int o = 128; o > 0; o >>= 1) {
    if (tid < o) { sua[tid] += sua[tid + o]; sub[tid] += sub[tid + o]; }
    __syncthreads();
  }
  __shared__ unsigned int sh_k;
  if (tid == 0) {
    const unsigned long long k10 = 10ull * (unsigned long long)sua[0];
    sh_k = (k10 < (unsigned long long)sub[0]) ? (unsigned int)k10 : sub[0];
  }
  __syncthreads();

  // count-only 256-bin scan -> sel_bin
  __shared__ unsigned int partC[256];
  __shared__ unsigned int sh_selb;
  const unsigned int ownC = hist[s * LBINS + tid];
  partC[tid] = ownC;
  __syncthreads();
  for (int o = 1; o < 256; o <<= 1) {
    const unsigned int aC = (tid >= o) ? partC[tid - o] : 0u;
    __syncthreads();
    partC[tid] += aC;
    __syncthreads();
  }
  {
    const unsigned int k = sh_k;
    const unsigned int inclC = partC[tid];
    const unsigned int exclC = inclC - ownC;
    if (ownC && k >= exclC && k < inclC) sh_selb = (unsigned int)tid;
  }
  __syncthreads();

  // gather candidates (2 float4/thread; block-aggregated reservation)
  __shared__ unsigned int cbuf[512];
  __shared__ unsigned int ccnt, cbase;
  if (tid == 0) ccnt = 0u;
  __syncthreads();
  {
    const unsigned int bsel = sh_selb;
#pragma unroll
    for (int g = 0; g < 2; ++g) {
      const int q = (rel * 512 + g * 256 + tid) * 4;
      const float4 v4 = *(const float4*)(npv + base + q);
      const float va[4] = {v4.x, v4.y, v4.z, v4.w};
#pragma unroll
      for (int j = 0; j < 4; ++j) {
        if (lin_bin(va[j]) == bsel) {
          const unsigned int sl = atomicAdd(&ccnt, 1u);
          if (sl < 512u) {
            cbuf[sl] = __float_as_uint(va[j]);
          } else {  // overflow fallback (rare)
            const unsigned int g2 = atomicAdd(&cand_cnt[s], 1u);
            if (g2 < (unsigned)CAP) cand[s * CAP + g2] = __float_as_uint(va[j]);
          }
        }
      }
    }
  }
  __syncthreads();
  if (tid == 0) {
    const unsigned int n = min(ccnt, 512u);
    cbase = n ? atomicAdd(&cand_cnt[s], n) : 0u;
  }
  __syncthreads();
  {
    const unsigned int n = min(ccnt, 512u);
    for (unsigned int i = tid; i < n; i += 256) {
      const unsigned int idx = cbase + i;
      if (idx < (unsigned)CAP) cand[s * CAP + idx] = cbuf[i];
    }
  }
}

// ------- pass 3: 3 blocks -- reduce + dual scan + radix select + finalize ---
__global__ __launch_bounds__(256) void k_select(
    const double* __restrict__ posce_a, const double* __restrict__ diff2_a,
    const unsigned int* __restrict__ pcnt_a,
    const unsigned int* __restrict__ ncnt_a,
    const unsigned int* __restrict__ hist, const float* __restrict__ histce,
    const unsigned int* __restrict__ cand_cnt,
    const unsigned int* __restrict__ cand, float* __restrict__ out) {
  const int s = blockIdx.x;
  const int tid = threadIdx.x;
  const int lo = (s == 0) ? 0 : (s == 1) ? B0 : B0 + B1;
  const int hi = (s == 0) ? B0 : (s == 1) ? B0 + B1 : NBLK;

  __shared__ double sda[256], sdb[256];
  __shared__ unsigned int sua[256], sub[256];
  {
    double a = 0.0, b2 = 0.0;
    unsigned int c = 0, d = 0;
    for (int i = lo + tid; i < hi; i += 256) {
      a += posce_a[i]; b2 += diff2_a[i];
      c += pcnt_a[i];  d += ncnt_a[i];
    }
    sda[tid] = a; sdb[tid] = b2; sua[tid] = c; sub[tid] = d;
  }
  __syncthreads();
  for (int o = 128; o > 0; o >>= 1) {
    if (tid < o) {
      sda[tid] += sda[tid + o]; sdb[tid] += sdb[tid + o];
      sua[tid] += sua[tid + o]; sub[tid] += sub[tid + o];
    }
    __syncthreads();
  }
  __shared__ double sh_posce, sh_diff2;
  __shared__ unsigned int sh_pcnt, sh_k;
  if (tid == 0) {
    sh_posce = sda[0];
    sh_diff2 = sdb[0];
    sh_pcnt = sua[0];
    const unsigned long long k10 = 10ull * (unsigned long long)sua[0];
    sh_k = (k10 < (unsigned long long)sub[0]) ? (unsigned int)k10 : sub[0];
  }
  __syncthreads();

  // dual 256-bin scan -> selb, selr, ce_below
  __shared__ unsigned int partC[256];
  __shared__ double partE[256];
  __shared__ unsigned int sh_selb, sh_selr;
  __shared__ double sh_ceb;
  const unsigned int ownC = hist[s * LBINS + tid];
  const double ownE = (double)histce[s * LBINS + tid];
  partC[tid] = ownC;
  partE[tid] = ownE;
  __syncthreads();
  for (int o = 1; o < 256; o <<= 1) {
    const unsigned int aC = (tid >= o) ? partC[tid - o] : 0u;
    const double aE = (tid >= o) ? partE[tid - o] : 0.0;
    __syncthreads();
    partC[tid] += aC;
    partE[tid] += aE;
    __syncthreads();
  }
  {
    const unsigned int k = sh_k;
    const unsigned int inclC = partC[tid];
    const unsigned int exclC = inclC - ownC;
    if (ownC && k >= exclC && k < inclC) {
      sh_selb = (unsigned int)tid;
      sh_selr = k - exclC;
      sh_ceb = partE[tid] - ownE;
    }
  }
  __syncthreads();

  // exact radix select over candidates
  const unsigned int n = min(cand_cnt[s], (unsigned int)CAP);
  const unsigned int* lst = cand + s * CAP;
  __shared__ unsigned int dh[256];
  __shared__ unsigned int shp, shr, sh_w8, sh_nr;
  if (tid == 0) {
    shr = sh_selr;
    // bins >=1 span one binade -> candidates share bits 31:24
    shp = (sh_selb >= 1u) ? (lst[0] & 0xFF000000u) : 0u;
  }
  __syncthreads();
  const int r0 = (sh_selb >= 1u) ? 1 : 0;
  for (int round = r0; round < 4; ++round) {
    const int shift = 24 - 8 * round;
    dh[tid] = 0u;
    __syncthreads();
    const unsigned int pref = shp;
    for (unsigned int i = tid; i < n; i += 256) {
      const unsigned int v = lst[i];
      const bool match =
          (round == 0) || ((v >> (shift + 8)) == (pref >> (shift + 8)));
      if (match) atomicAdd(&dh[(v >> shift) & 255u], 1u);
    }
    __syncthreads();
    const unsigned int own = dh[tid];
    for (int o = 1; o < 256; o <<= 1) {  // inclusive scan in place
      const unsigned int add = (tid >= o) ? dh[tid - o] : 0u;
      __syncthreads();
      dh[tid] += add;
      __syncthreads();
    }
    const unsigned int incl = dh[tid];
    const unsigned int excl = incl - own;
    const unsigned int k = shr;
    if (own && k >= excl && k < incl) {
      sh_w8 = (unsigned int)tid;
      sh_nr = k - excl;
    }
    __syncthreads();
    if (tid == 0) {
      shp = pref | (sh_w8 << shift);
      shr = sh_nr;
    }
    __syncthreads();
  }
  const float thr = __uint_as_float(shp);

  // in-bin CE: candidates with 0 < v <= thr
  double acc = 0.0;
  for (unsigned int i = tid; i < n; i += 256) {
    const float v = __uint_as_float(lst[i]);
    if (v > 0.0f && v <= thr) acc += (double)(-logf(v));
  }
  sda[tid] = acc;
  __syncthreads();
  for (int o = 128; o > 0; o >>= 1) {
    if (tid < o) sda[tid] += sda[tid + o];
    __syncthreads();
  }
  if (tid == 0) {
    const double Ns = (s == 0) ? (double)N0 : (s == 1) ? (double)N1 : (double)N2;
    const double W = (s == 0) ? 160.0 : (s == 1) ? 80.0 : 40.0;
    const double ls = (sh_posce + sh_ceb + sda[0]) / (2.0 * Ns);
    const double lb = (sh_diff2 / W) / (4.0 * (double)sh_pcnt);
    out[s] = (float)(ls + lb);
  }
}

extern "C" void kernel_launch(void* const* d_in, const int* in_sizes, int n_in,
                              void* d_out, int out_size, void* d_ws,
                              size_t ws_size, hipStream_t stream) {
  const float* sc0 = (const float*)d_in[0];
  const float* bb0 = (const float*)d_in[1];
  const float* gl0 = (const float*)d_in[3];
  const float* sc1 = (const float*)d_in[4];
  const float* bb1 = (const float*)d_in[5];
  const float* gl1 = (const float*)d_in[7];
  const float* sc2 = (const float*)d_in[8];
  const float* bb2 = (const float*)d_in[9];
  const float* gl2 = (const float*)d_in[11];

  char* ws = (char*)d_ws;
  unsigned int* hist = (unsigned int*)ws;              // 3*256 u32
  float* histce = (float*)(hist + 3 * LBINS);          // 3*256 f32
  unsigned int* cand_cnt = (unsigned int*)(histce + 3 * LBINS);  // 4 u32
  size_t zbytes = (size_t)3 * LBINS * 4 * 2 + 16;      // zeroed region
  zbytes = (zbytes + 255) & ~(size_t)255;
  size_t off = zbytes;
  double* posce_a = (double*)(ws + off);  off += (size_t)NBLK * 8;
  double* diff2_a = (double*)(ws + off);  off += (size_t)NBLK * 8;
  unsigned int* pcnt_a = (unsigned int*)(ws + off);  off += (size_t)NBLK * 4;
  unsigned int* ncnt_a = (unsigned int*)(ws + off);  off += (size_t)NBLK * 4;
  off = (off + 255) & ~(size_t)255;
  unsigned int* cand = (unsigned int*)(ws + off);      // 3*CAP u32
  off += (size_t)3 * CAP * 4;
  off = (off + 255) & ~(size_t)255;
  float* npv = (float*)(ws + off);                     // NT floats

  const dim3 blk(256);
  k_zero<<<dim3(1), blk, 0, stream>>>((uint4*)d_ws, (int)(zbytes >> 4));
  k_pass1<<<dim3(NBLK), blk, 0, stream>>>(sc0, bb0, gl0, sc1, bb1, gl1, sc2,
                                          bb2, gl2, hist, histce, npv, posce_a,
                                          diff2_a, pcnt_a, ncnt_a);
  k_cand<<<dim3(NBLK), blk, 0, stream>>>(pcnt_a, ncnt_a, hist, npv, cand_cnt,
                                         cand);
  k_select<<<dim3(3), blk, 0, stream>>>(posce_a, diff2_a, pcnt_a, ncnt_a, hist,
                                        histce, cand_cnt, cand, (float*)d_out);
}

// Round 13
// 54.076 us; speedup vs baseline: 1.6888x; 1.0564x over previous
//
#include <hip/hip_runtime.h>

// ---------------------------------------------------------------------------
// cross_entropy_with_hnm_for_one_class_detection
//
// 3 scales: softmax-CE with hard-negative mining (k-th order statistic of
// neg_prob over N=B*H*W) + masked bbox MSE. Output: 3 floats.
//
// R12 analysis: pass1's long pole = 16 LDS atomics/thread (count + f32-CE
// histograms) + npv store stream; inputs are L3-hot so recompute < round-trip.
// R13: pass1 keeps ONLY the count hist (8 LDS atomics, no bulk stores);
// k_cand recomputes d/v bitwise-identically from sc+gl, sums ce for bins <
// sel_bin into per-block f64 slots, and gathers in-bin candidates; k_select
// reduces partials + radix select + finalize. No fences, 4 launches.
// ---------------------------------------------------------------------------

namespace {
constexpr int HW0 = 25600, HW1 = 6400, HW2 = 1600;
constexpr int N0 = 32 * HW0;  // 819200
constexpr int N1 = 32 * HW1;  // 204800
constexpr int N2 = 32 * HW2;  // 51200

constexpr int LBINS = 256;
constexpr int CAP = 8192;  // candidate capacity per scale

// 2048 elements per block (two float4-quads per thread)
constexpr int B0 = N0 / 2048, B1 = N1 / 2048, B2 = N2 / 2048;  // 400,100,25
constexpr int NBLK = B0 + B1 + B2;                             // 525

__device__ __forceinline__ void scale_of(int bid, int& s, int& rel, int& lo,
                                         int& hi) {
  if (bid < B0) {
    s = 0; rel = bid; lo = 0; hi = B0;
  } else if (bid < B0 + B1) {
    s = 1; rel = bid - B0; lo = B0; hi = B0 + B1;
  } else {
    s = 2; rel = bid - B0 - B1; lo = B0 + B1; hi = NBLK;
  }
}

__device__ __forceinline__ unsigned int lin_bin(float v) {
  unsigned int b = (unsigned int)(v * 256.0f);
  return b > 255u ? 255u : b;
}
}  // namespace

// ---------------- pass 0: zero control region (~3.3 KB) ---------------------
__global__ __launch_bounds__(256) void k_zero(uint4* __restrict__ p, int n4) {
  for (int i = threadIdx.x; i < n4; i += 256) p[i] = make_uint4(0u, 0u, 0u, 0u);
}

// ------- pass 1: softmax stats, counts, pos-CE, bbox, count hist ------------
template <int HW>
__device__ void p1_main(int rel, const float* __restrict__ sc,
                        const float* __restrict__ bb,
                        const float* __restrict__ gl,
                        unsigned int* __restrict__ histS,
                        double* __restrict__ posce_o,
                        double* __restrict__ diff2_o,
                        unsigned int* __restrict__ pcnt_o,
                        unsigned int* __restrict__ ncnt_o) {
  __shared__ unsigned int lh[4][LBINS];  // wave-private count hists, 4 KiB
  const int tid = threadIdx.x, wid = tid >> 6;
#pragma unroll
  for (int w = 0; w < 4; ++w) lh[w][tid] = 0u;
  __syncthreads();

  // two quad-groups; all 8 coalesced loads issued before any math
  const int q0 = (rel * 512 + tid) * 4;
  const int q1 = q0 + 1024;
  const int bA = q0 / HW, hwA = q0 - bA * HW;
  const int bB = q1 / HW, hwB = q1 - bB * HW;
  const float* scA = sc + (size_t)bA * 2 * HW + hwA;
  const float* scB = sc + (size_t)bB * 2 * HW + hwB;
  const float* glA = gl + (size_t)bA * 6 * HW + hwA;
  const float* glB = gl + (size_t)bB * 6 * HW + hwB;
  const float4 s0A = *(const float4*)scA;
  const float4 s1A = *(const float4*)(scA + HW);
  const float4 l0A = *(const float4*)glA;
  const float4 l1A = *(const float4*)(glA + HW);
  const float4 s0B = *(const float4*)scB;
  const float4 s1B = *(const float4*)(scB + HW);
  const float4 l0B = *(const float4*)glB;
  const float4 l1B = *(const float4*)(glB + HW);

  double posce = 0.0, diff2 = 0.0;
  unsigned int pcnt = 0, ncnt = 0;

  auto process = [&](const float4& s0v, const float4& s1v, const float4& l0v,
                     const float4& l1v, const float* __restrict__ glq,
                     const float* __restrict__ bbq) {
    const float s0a[4] = {s0v.x, s0v.y, s0v.z, s0v.w};
    const float s1a[4] = {s1v.x, s1v.y, s1v.z, s1v.w};
    const float l0a[4] = {l0v.x, l0v.y, l0v.z, l0v.w};
    const float l1a[4] = {l1v.x, l1v.y, l1v.z, l1v.w};
#pragma unroll
    for (int j = 0; j < 4; ++j) {
      const float d = s1a[j] - s0a[j];
      const float t = expf(-fabsf(d));
      const float l1p = log1pf(t);  // lse after max-sub
      const bool pos = l0a[j] > 0.5f;
      const bool neg = l1a[j] > 0.5f;
      const float sm1 = ((d >= 0.0f) ? 1.0f : t) / (1.0f + t);
      const float v = neg ? sm1 : 0.0f;
      atomicAdd(&lh[wid][lin_bin(v)], 1u);
      if (neg) ncnt++;
      if (pos) {
        pcnt++;
        posce += (double)(-l0a[j] * (((d > 0.0f) ? -d : 0.0f) - l1p));
        float acc = 0.0f;
#pragma unroll
        for (int c = 0; c < 4; ++c) {
          const float dd = glq[(2 + c) * HW + j] - bbq[c * HW + j];
          acc += dd * dd;
        }
        diff2 += (double)acc;
      }
    }
  };
  process(s0A, s1A, l0A, l1A, glA, bb + (size_t)bA * 4 * HW + hwA);
  process(s0B, s1B, l0B, l1B, glB, bb + (size_t)bB * 4 * HW + hwB);

  __syncthreads();
  {  // flush counts: one bin per thread
    const unsigned int c = lh[0][tid] + lh[1][tid] + lh[2][tid] + lh[3][tid];
    if (c) atomicAdd(&histS[tid], c);
  }

  // reduce partials -> per-block SoA slots (no global atomics)
  for (int o = 32; o > 0; o >>= 1) {
    posce += __shfl_down(posce, o, 64);
    diff2 += __shfl_down(diff2, o, 64);
    pcnt += __shfl_down(pcnt, o, 64);
    ncnt += __shfl_down(ncnt, o, 64);
  }
  __shared__ double wa[4], wb[4];
  __shared__ unsigned int wc[4], wd[4];
  if ((tid & 63) == 0) {
    wa[wid] = posce; wb[wid] = diff2; wc[wid] = pcnt; wd[wid] = ncnt;
  }
  __syncthreads();
  if (tid == 0) {
    *posce_o = wa[0] + wa[1] + wa[2] + wa[3];
    *diff2_o = wb[0] + wb[1] + wb[2] + wb[3];
    *pcnt_o = wc[0] + wc[1] + wc[2] + wc[3];
    *ncnt_o = wd[0] + wd[1] + wd[2] + wd[3];
  }
}

__global__ __launch_bounds__(256) void k_pass1(
    const float* sc0, const float* bb0, const float* gl0,
    const float* sc1, const float* bb1, const float* gl1,
    const float* sc2, const float* bb2, const float* gl2,
    unsigned int* hist, double* posce_a, double* diff2_a,
    unsigned int* pcnt_a, unsigned int* ncnt_a) {
  int s, rel, lo, hi;
  scale_of(blockIdx.x, s, rel, lo, hi);
  const int bid = blockIdx.x;
  if (s == 0)
    p1_main<HW0>(rel, sc0, bb0, gl0, hist, posce_a + bid, diff2_a + bid,
                 pcnt_a + bid, ncnt_a + bid);
  else if (s == 1)
    p1_main<HW1>(rel, sc1, bb1, gl1, hist + LBINS, posce_a + bid,
                 diff2_a + bid, pcnt_a + bid, ncnt_a + bid);
  else
    p1_main<HW2>(rel, sc2, bb2, gl2, hist + 2 * LBINS, posce_a + bid,
                 diff2_a + bid, pcnt_a + bid, ncnt_a + bid);
}

// --- pass 2: recompute v; ce-below partial; gather in-bin candidates --------
template <int HW>
__device__ void p2_main(int rel, int s, int lo, int hi,
                        const float* __restrict__ sc,
                        const float* __restrict__ gl,
                        const unsigned int* __restrict__ pcnt_a,
                        const unsigned int* __restrict__ ncnt_a,
                        const unsigned int* __restrict__ hist,
                        double* __restrict__ ceb_o,
                        unsigned int* __restrict__ cand_cnt,
                        unsigned int* __restrict__ cand) {
  const int tid = threadIdx.x;

  // issue the 6 bulk loads first; they stay in flight across the scan
  const int q0 = (rel * 512 + tid) * 4;
  const int q1 = q0 + 1024;
  const int bA = q0 / HW, hwA = q0 - bA * HW;
  const int bB = q1 / HW, hwB = q1 - bB * HW;
  const float* scA = sc + (size_t)bA * 2 * HW + hwA;
  const float* scB = sc + (size_t)bB * 2 * HW + hwB;
  const float4 s0A = *(const float4*)scA;
  const float4 s1A = *(const float4*)(scA + HW);
  const float4 l1A = *(const float4*)(gl + (size_t)bA * 6 * HW + HW + hwA);
  const float4 s0B = *(const float4*)scB;
  const float4 s1B = *(const float4*)(scB + HW);
  const float4 l1B = *(const float4*)(gl + (size_t)bB * 6 * HW + HW + hwB);

  // redundant count reduce (L2-hot, ~4 KB)
  __shared__ unsigned int sua[256], sub[256];
  {
    unsigned int c = 0, d = 0;
    for (int i = lo + tid; i < hi; i += 256) {
      c += pcnt_a[i];
      d += ncnt_a[i];
    }
    sua[tid] = c; sub[tid] = d;
  }
  __syncthreads();
  for (int o = 128; o > 0; o >>= 1) {
    if (tid < o) { sua[tid] += sua[tid + o]; sub[tid] += sub[tid + o]; }
    __syncthreads();
  }
  __shared__ unsigned int sh_k;
  if (tid == 0) {
    const unsigned long long k10 = 10ull * (unsigned long long)sua[0];
    sh_k = (k10 < (unsigned long long)sub[0]) ? (unsigned int)k10 : sub[0];
  }
  __syncthreads();

  // count-only 256-bin scan -> sel_bin
  __shared__ unsigned int partC[256];
  __shared__ unsigned int sh_selb;
  const unsigned int ownC = hist[s * LBINS + tid];
  partC[tid] = ownC;
  __syncthreads();
  for (int o = 1; o < 256; o <<= 1) {
    const unsigned int aC = (tid >= o) ? partC[tid - o] : 0u;
    __syncthreads();
    partC[tid] += aC;
    __syncthreads();
  }
  {
    const unsigned int k = sh_k;
    const unsigned int inclC = partC[tid];
    const unsigned int exclC = inclC - ownC;
    if (ownC && k >= exclC && k < inclC) sh_selb = (unsigned int)tid;
  }
  __syncthreads();

  // recompute v (bitwise == pass1), sum ce for bins < selb, gather in-bin
  __shared__ unsigned int cbuf[512];
  __shared__ unsigned int ccnt, cbase;
  if (tid == 0) ccnt = 0u;
  __syncthreads();
  const unsigned int bsel = sh_selb;
  double ceb = 0.0;

  auto scan8 = [&](const float4& s0v, const float4& s1v, const float4& l1v) {
    const float s0a[4] = {s0v.x, s0v.y, s0v.z, s0v.w};
    const float s1a[4] = {s1v.x, s1v.y, s1v.z, s1v.w};
    const float l1a[4] = {l1v.x, l1v.y, l1v.z, l1v.w};
#pragma unroll
    for (int j = 0; j < 4; ++j) {
      const float d = s1a[j] - s0a[j];
      const bool neg = l1a[j] > 0.5f;
      if (!neg) continue;  // v = 0: bin 0; ce contribution 0 either way
      const float t = expf(-fabsf(d));
      const float v = ((d >= 0.0f) ? 1.0f : t) / (1.0f + t);
      const unsigned int bin = lin_bin(v);
      if (bin < bsel) {
        ceb += (double)(log1pf(t) - ((d >= 0.0f) ? 0.0f : d));
      } else if (bin == bsel) {
        const unsigned int sl = atomicAdd(&ccnt, 1u);
        if (sl < 512u) {
          cbuf[sl] = __float_as_uint(v);
        } else {  // overflow fallback (rare)
          const unsigned int g2 = atomicAdd(&cand_cnt[s], 1u);
          if (g2 < (unsigned)CAP) cand[s * CAP + g2] = __float_as_uint(v);
        }
      }
    }
  };
  scan8(s0A, s1A, l1A);
  scan8(s0B, s1B, l1B);
  __syncthreads();
  if (tid == 0) {
    const unsigned int n = min(ccnt, 512u);
    cbase = n ? atomicAdd(&cand_cnt[s], n) : 0u;
  }
  __syncthreads();
  {
    const unsigned int n = min(ccnt, 512u);
    for (unsigned int i = tid; i < n; i += 256) {
      const unsigned int idx = cbase + i;
      if (idx < (unsigned)CAP) cand[s * CAP + idx] = cbuf[i];
    }
  }

  // reduce ceb -> per-block slot
  for (int o = 32; o > 0; o >>= 1) ceb += __shfl_down(ceb, o, 64);
  __shared__ double wv[4];
  if ((tid & 63) == 0) wv[tid >> 6] = ceb;
  __syncthreads();
  if (tid == 0) *ceb_o = wv[0] + wv[1] + wv[2] + wv[3];
}

__global__ __launch_bounds__(256) void k_cand(
    const float* sc0, const float* gl0, const float* sc1, const float* gl1,
    const float* sc2, const float* gl2,
    const unsigned int* __restrict__ pcnt_a,
    const unsigned int* __restrict__ ncnt_a,
    const unsigned int* __restrict__ hist, double* __restrict__ ceb_a,
    unsigned int* __restrict__ cand_cnt, unsigned int* __restrict__ cand) {
  int s, rel, lo, hi;
  scale_of(blockIdx.x, s, rel, lo, hi);
  const int bid = blockIdx.x;
  if (s == 0)
    p2_main<HW0>(rel, 0, lo, hi, sc0, gl0, pcnt_a, ncnt_a, hist, ceb_a + bid,
                 cand_cnt, cand);
  else if (s == 1)
    p2_main<HW1>(rel, 1, lo, hi, sc1, gl1, pcnt_a, ncnt_a, hist, ceb_a + bid,
                 cand_cnt, cand);
  else
    p2_main<HW2>(rel, 2, lo, hi, sc2, gl2, pcnt_a, ncnt_a, hist, ceb_a + bid,
                 cand_cnt, cand);
}

// ------- pass 3: 3 blocks -- reduce + scan + radix select + finalize --------
__global__ __launch_bounds__(256) void k_select(
    const double* __restrict__ posce_a, const double* __restrict__ diff2_a,
    const double* __restrict__ ceb_a, const unsigned int* __restrict__ pcnt_a,
    const unsigned int* __restrict__ ncnt_a,
    const unsigned int* __restrict__ hist,
    const unsigned int* __restrict__ cand_cnt,
    const unsigned int* __restrict__ cand, float* __restrict__ out) {
  const int s = blockIdx.x;
  const int tid = threadIdx.x;
  const int lo = (s == 0) ? 0 : (s == 1) ? B0 : B0 + B1;
  const int hi = (s == 0) ? B0 : (s == 1) ? B0 + B1 : NBLK;

  __shared__ double sda[256], sdb[256], sdc[256];
  __shared__ unsigned int sua[256], sub[256];
  {
    double a = 0.0, b2 = 0.0, e = 0.0;
    unsigned int c = 0, d = 0;
    for (int i = lo + tid; i < hi; i += 256) {
      a += posce_a[i]; b2 += diff2_a[i]; e += ceb_a[i];
      c += pcnt_a[i];  d += ncnt_a[i];
    }
    sda[tid] = a; sdb[tid] = b2; sdc[tid] = e; sua[tid] = c; sub[tid] = d;
  }
  __syncthreads();
  for (int o = 128; o > 0; o >>= 1) {
    if (tid < o) {
      sda[tid] += sda[tid + o]; sdb[tid] += sdb[tid + o];
      sdc[tid] += sdc[tid + o];
      sua[tid] += sua[tid + o]; sub[tid] += sub[tid + o];
    }
    __syncthreads();
  }
  __shared__ double sh_posce, sh_diff2, sh_ceb;
  __shared__ unsigned int sh_pcnt, sh_k;
  if (tid == 0) {
    sh_posce = sda[0];
    sh_diff2 = sdb[0];
    sh_ceb = sdc[0];
    sh_pcnt = sua[0];
    const unsigned long long k10 = 10ull * (unsigned long long)sua[0];
    sh_k = (k10 < (unsigned long long)sub[0]) ? (unsigned int)k10 : sub[0];
  }
  __syncthreads();

  // count-only 256-bin scan -> selb, selr
  __shared__ unsigned int partC[256];
  __shared__ unsigned int sh_selb, sh_selr;
  const unsigned int ownC = hist[s * LBINS + tid];
  partC[tid] = ownC;
  __syncthreads();
  for (int o = 1; o < 256; o <<= 1) {
    const unsigned int aC = (tid >= o) ? partC[tid - o] : 0u;
    __syncthreads();
    partC[tid] += aC;
    __syncthreads();
  }
  {
    const unsigned int k = sh_k;
    const unsigned int inclC = partC[tid];
    const unsigned int exclC = inclC - ownC;
    if (ownC && k >= exclC && k < inclC) {
      sh_selb = (unsigned int)tid;
      sh_selr = k - exclC;
    }
  }
  __syncthreads();

  // exact radix select over candidates
  const unsigned int n = min(cand_cnt[s], (unsigned int)CAP);
  const unsigned int* lst = cand + s * CAP;
  __shared__ unsigned int dh[256];
  __shared__ unsigned int shp, shr, sh_w8, sh_nr;
  if (tid == 0) {
    shr = sh_selr;
    // bins >=1 span one binade -> candidates share bits 31:24
    shp = (sh_selb >= 1u) ? (lst[0] & 0xFF000000u) : 0u;
  }
  __syncthreads();
  const int r0 = (sh_selb >= 1u) ? 1 : 0;
  for (int round = r0; round < 4; ++round) {
    const int shift = 24 - 8 * round;
    dh[tid] = 0u;
    __syncthreads();
    const unsigned int pref = shp;
    for (unsigned int i = tid; i < n; i += 256) {
      const unsigned int v = lst[i];
      const bool match =
          (round == 0) || ((v >> (shift + 8)) == (pref >> (shift + 8)));
      if (match) atomicAdd(&dh[(v >> shift) & 255u], 1u);
    }
    __syncthreads();
    const unsigned int own = dh[tid];
    for (int o = 1; o < 256; o <<= 1) {  // inclusive scan in place
      const unsigned int add = (tid >= o) ? dh[tid - o] : 0u;
      __syncthreads();
      dh[tid] += add;
      __syncthreads();
    }
    const unsigned int incl = dh[tid];
    const unsigned int excl = incl - own;
    const unsigned int k = shr;
    if (own && k >= excl && k < incl) {
      sh_w8 = (unsigned int)tid;
      sh_nr = k - excl;
    }
    __syncthreads();
    if (tid == 0) {
      shp = pref | (sh_w8 << shift);
      shr = sh_nr;
    }
    __syncthreads();
  }
  const float thr = __uint_as_float(shp);

  // in-bin CE: candidates with 0 < v <= thr
  double acc = 0.0;
  for (unsigned int i = tid; i < n; i += 256) {
    const float v = __uint_as_float(lst[i]);
    if (v > 0.0f && v <= thr) acc += (double)(-logf(v));
  }
  sda[tid] = acc;
  __syncthreads();
  for (int o = 128; o > 0; o >>= 1) {
    if (tid < o) sda[tid] += sda[tid + o];
    __syncthreads();
  }
  if (tid == 0) {
    const double Ns = (s == 0) ? (double)N0 : (s == 1) ? (double)N1 : (double)N2;
    const double W = (s == 0) ? 160.0 : (s == 1) ? 80.0 : 40.0;
    const double ls = (sh_posce + sh_ceb + sda[0]) / (2.0 * Ns);
    const double lb = (sh_diff2 / W) / (4.0 * (double)sh_pcnt);
    out[s] = (float)(ls + lb);
  }
}

extern "C" void kernel_launch(void* const* d_in, const int* in_sizes, int n_in,
                              void* d_out, int out_size, void* d_ws,
                              size_t ws_size, hipStream_t stream) {
  const float* sc0 = (const float*)d_in[0];
  const float* bb0 = (const float*)d_in[1];
  const float* gl0 = (const float*)d_in[3];
  const float* sc1 = (const float*)d_in[4];
  const float* bb1 = (const float*)d_in[5];
  const float* gl1 = (const float*)d_in[7];
  const float* sc2 = (const float*)d_in[8];
  const float* bb2 = (const float*)d_in[9];
  const float* gl2 = (const float*)d_in[11];

  char* ws = (char*)d_ws;
  unsigned int* hist = (unsigned int*)ws;              // 3*256 u32
  unsigned int* cand_cnt = hist + 3 * LBINS;           // 4 u32
  size_t zbytes = (size_t)3 * LBINS * 4 + 16;          // zeroed region
  zbytes = (zbytes + 255) & ~(size_t)255;
  size_t off = zbytes;
  double* posce_a = (double*)(ws + off);  off += (size_t)NBLK * 8;
  double* diff2_a = (double*)(ws + off);  off += (size_t)NBLK * 8;
  double* ceb_a = (double*)(ws + off);    off += (size_t)NBLK * 8;
  unsigned int* pcnt_a = (unsigned int*)(ws + off);  off += (size_t)NBLK * 4;
  unsigned int* ncnt_a = (unsigned int*)(ws + off);  off += (size_t)NBLK * 4;
  off = (off + 255) & ~(size_t)255;
  unsigned int* cand = (unsigned int*)(ws + off);      // 3*CAP u32

  const dim3 blk(256);
  k_zero<<<dim3(1), blk, 0, stream>>>((uint4*)d_ws, (int)(zbytes >> 4));
  k_pass1<<<dim3(NBLK), blk, 0, stream>>>(sc0, bb0, gl0, sc1, bb1, gl1, sc2,
                                          bb2, gl2, hist, posce_a, diff2_a,
                                          pcnt_a, ncnt_a);
  k_cand<<<dim3(NBLK), blk, 0, stream>>>(sc0, gl0, sc1, gl1, sc2, gl2, pcnt_a,
                                         ncnt_a, hist, ceb_a, cand_cnt, cand);
  k_select<<<dim3(3), blk, 0, stream>>>(posce_a, diff2_a, ceb_a, pcnt_a,
                                        ncnt_a, hist, cand_cnt, cand,
                                        (float*)d_out);
}